// Round 2
// baseline (5146.204 us; speedup 1.0000x reference)
//
#include <hip/hip_runtime.h>
#include <cmath>

constexpr int NB   = 16;      // batch
constexpr int NPTS = 10000;   // points per batch
constexpr int NBN  = NB * NPTS;   // 160000
constexpr int NS_ITERS = 18;

// ---------------------------------------------------------------------------
// Layer 0: 3 -> 64, no input BN
// ---------------------------------------------------------------------------
__global__ __launch_bounds__(256) void conv0_ker(const float* __restrict__ pts,
                                                 const float* __restrict__ W,
                                                 float* __restrict__ y) {
    int g = blockIdx.x * 256 + threadIdx.x;          // 0..159999
    int b = g / NPTS;
    int n = g - b * NPTS;
    float p0 = pts[3 * (size_t)g + 0];
    float p1 = pts[3 * (size_t)g + 1];
    float p2 = pts[3 * (size_t)g + 2];
    float* yp = y + ((size_t)b * 64) * NPTS + n;
    for (int o = 0; o < 64; ++o) {
        float v = W[3 * o] * p0 + W[3 * o + 1] * p1 + W[3 * o + 2] * p2;
        yp[(size_t)o * NPTS] = v;
    }
}

// ---------------------------------------------------------------------------
// Generic conv layer: x = relu(prev*scale+shift); y = W x
// ---------------------------------------------------------------------------
template <int CIN, int COUT>
__global__ __launch_bounds__(256) void conv_bn_relu(const float* __restrict__ xin,
                                                    const float* __restrict__ ss,
                                                    const float* __restrict__ W,
                                                    float* __restrict__ y) {
    int g = blockIdx.x * 256 + threadIdx.x;
    int b = g / NPTS;
    int n = g - b * NPTS;
    const float* xp = xin + ((size_t)b * CIN) * NPTS + n;
    float xr[CIN];
#pragma unroll
    for (int c = 0; c < CIN; ++c) {
        float v = xp[(size_t)c * NPTS];
        v = fmaf(v, ss[c], ss[256 + c]);
        xr[c] = fmaxf(v, 0.f);
    }
    float* yp = y + ((size_t)b * COUT) * NPTS + n;
#pragma unroll 1
    for (int o = 0; o < COUT; ++o) {
        const float* wrow = W + o * CIN;
        float a0 = 0.f, a1 = 0.f, a2 = 0.f, a3 = 0.f;
#pragma unroll
        for (int c = 0; c < CIN; c += 4) {
            a0 = fmaf(wrow[c + 0], xr[c + 0], a0);
            a1 = fmaf(wrow[c + 1], xr[c + 1], a1);
            a2 = fmaf(wrow[c + 2], xr[c + 2], a2);
            a3 = fmaf(wrow[c + 3], xr[c + 3], a3);
        }
        yp[(size_t)o * NPTS] = (a0 + a1) + (a2 + a3);
    }
}

// ---------------------------------------------------------------------------
// Per-channel sum / sumsq over (batch, points)  -> stats[c], stats[C+c]
// ---------------------------------------------------------------------------
__global__ void chan_stats(const float* __restrict__ y, int C, float* __restrict__ stats) {
    int c = blockIdx.x, b = blockIdx.y, t = threadIdx.x;
    const float* p = y + ((size_t)(b * C + c)) * NPTS;
    float s = 0.f, q = 0.f;
    for (int n = t; n < NPTS; n += 256) {
        float v = p[n];
        s += v;
        q = fmaf(v, v, q);
    }
    for (int off = 32; off; off >>= 1) {
        s += __shfl_down(s, off);
        q += __shfl_down(q, off);
    }
    __shared__ float ls[4], lq[4];
    if ((t & 63) == 0) { ls[t >> 6] = s; lq[t >> 6] = q; }
    __syncthreads();
    if (t == 0) {
        atomicAdd(&stats[c],     ls[0] + ls[1] + ls[2] + ls[3]);
        atomicAdd(&stats[C + c], lq[0] + lq[1] + lq[2] + lq[3]);
    }
}

__global__ void bn_finalize(const float* __restrict__ stats, const float* __restrict__ g,
                            const float* __restrict__ bi, int C, float* __restrict__ ss) {
    int c = threadIdx.x;
    if (c < C) {
        float mu  = stats[c] * (1.f / NBN);
        float var = stats[C + c] * (1.f / NBN) - mu * mu;
        float r = rsqrtf(var + 1e-5f);
        float s = g[c] * r;
        ss[c] = s;
        ss[256 + c] = bi[c] - mu * s;
    }
}

// ---------------------------------------------------------------------------
// Per-batch channel sums of final features f = relu(bn(y4))
// ---------------------------------------------------------------------------
__global__ void fsum_ker(const float* __restrict__ y4, const float* __restrict__ ss,
                         float* __restrict__ fsumb) {
    int c = blockIdx.x, b = blockIdx.y, t = threadIdx.x;
    const float* p = y4 + ((size_t)(b * 256 + c)) * NPTS;
    float sc = ss[c], sh = ss[256 + c];
    float s = 0.f;
    for (int n = t; n < NPTS; n += 256) {
        float v = fmaf(p[n], sc, sh);
        s += fmaxf(v, 0.f);
    }
    for (int off = 32; off; off >>= 1) s += __shfl_down(s, off);
    __shared__ float ls[4];
    if ((t & 63) == 0) ls[t >> 6] = s;
    __syncthreads();
    if (t == 0) fsumb[b * 256 + c] = ls[0] + ls[1] + ls[2] + ls[3];
}

// ---------------------------------------------------------------------------
// Raw second moment: covM[b] += F_b^T F_b  (128x128 tiles, N split in 8 chunks)
// grid: (8 chunks, 4 tiles, 16 batches)
// ---------------------------------------------------------------------------
__global__ __launch_bounds__(256) void cov_ker(const float* __restrict__ y4,
                                               const float* __restrict__ ss,
                                               float* __restrict__ covM) {
    int chunk = blockIdx.x;
    int tile  = blockIdx.y;
    int b     = blockIdx.z;
    int ti = tile >> 1, tj = tile & 1;
    int t = threadIdx.x;
    __shared__ float At[2][32][132];   // [half][point][channel], padded
    float acc[8][8];
#pragma unroll
    for (int i = 0; i < 8; ++i)
#pragma unroll
        for (int j = 0; j < 8; ++j) acc[i][j] = 0.f;

    int n0c = chunk * 1250;
    int r0 = (t & 15) * 8, c0 = (t >> 4) * 8;
    for (int pp = 0; pp < 40; ++pp) {
        int base = pp * 32;
        __syncthreads();
#pragma unroll
        for (int half = 0; half < 2; ++half) {
            int panel = (half ? tj : ti) * 128;
#pragma unroll
            for (int i = 0; i < 16; ++i) {
                int l = i * 256 + t;
                int c = l >> 5, p = l & 31;
                float v = 0.f;
                if (base + p < 1250) {
                    float raw = y4[((size_t)(b * 256 + panel + c)) * NPTS + n0c + base + p];
                    raw = fmaf(raw, ss[panel + c], ss[256 + panel + c]);
                    v = fmaxf(raw, 0.f);
                }
                At[half][p][c] = v;
            }
        }
        __syncthreads();
#pragma unroll 4
        for (int p = 0; p < 32; ++p) {
            float ar[8], ac[8];
#pragma unroll
            for (int i = 0; i < 8; ++i) ar[i] = At[0][p][r0 + i];
#pragma unroll
            for (int j = 0; j < 8; ++j) ac[j] = At[1][p][c0 + j];
#pragma unroll
            for (int i = 0; i < 8; ++i)
#pragma unroll
                for (int j = 0; j < 8; ++j) acc[i][j] = fmaf(ar[i], ac[j], acc[i][j]);
        }
    }
#pragma unroll
    for (int i = 0; i < 8; ++i)
#pragma unroll
        for (int j = 0; j < 8; ++j) {
            size_t idx = ((size_t)b << 16) + (size_t)(ti * 128 + r0 + i) * 256 + tj * 128 + c0 + j;
            atomicAdd(&covM[idx], acc[i][j]);
        }
}

// ---------------------------------------------------------------------------
// cov = M/N - m (.) fbar^T - fbar (.) m^T + m m^T ; trace via diagonal atomics
// grid: (256 rows, 16 batches), 256 threads = cols
// ---------------------------------------------------------------------------
__global__ void covfin_ker(const float* __restrict__ covM, const float* __restrict__ fsumb,
                           float* __restrict__ Y0, float* __restrict__ trace) {
    int r = blockIdx.x, b = blockIdx.y, c = threadIdx.x;
    float fbr = fsumb[b * 256 + r] * (1.f / NPTS);
    float fbc = fsumb[b * 256 + c] * (1.f / NPTS);
    float mr = 0.f, mc = 0.f;
    for (int q = 0; q < NB; ++q) {
        mr += fsumb[q * 256 + r];
        mc += fsumb[q * 256 + c];
    }
    mr *= (1.f / NBN);
    mc *= (1.f / NBN);
    size_t idx = ((size_t)b << 16) + ((size_t)r << 8) + c;
    float v = covM[idx] * (1.f / NPTS) - fbr * mc - mr * fbc + mr * mc;
    Y0[idx] = v;
    if (c == r) atomicAdd(&trace[b], v);
}

__global__ void ns_init(float* __restrict__ Y0, float* __restrict__ Z0,
                        const float* __restrict__ trace) {
    int i = blockIdx.x * 256 + threadIdx.x;   // 16*65536 total
    int b = i >> 16, rc = i & 65535;
    float inv = 1.f / trace[b];
    Y0[i] *= inv;
    Z0[i] = ((rc >> 8) == (rc & 255)) ? 1.f : 0.f;
}

// ---------------------------------------------------------------------------
// 256x256 batched GEMM tile body: O = diag*I + scale*(A.B), 64x64 tiles
// ---------------------------------------------------------------------------
__device__ __forceinline__ void gemm_body(const float* __restrict__ Ab,
                                          const float* __restrict__ Bb,
                                          float* __restrict__ Ob,
                                          float scale, float diag, int tile, int t,
                                          float (*Al)[68], float (*Bl)[68]) {
    int tr = (tile >> 2) * 64, tc = (tile & 3) * 64;
    int r0 = (t & 15) * 4, c0 = (t >> 4) * 4;
    float acc[4][4];
#pragma unroll
    for (int i = 0; i < 4; ++i)
#pragma unroll
        for (int j = 0; j < 4; ++j) acc[i][j] = 0.f;

    for (int kc = 0; kc < 256; kc += 64) {
        __syncthreads();
#pragma unroll
        for (int i = 0; i < 16; ++i) {
            int l = i * 256 + t;
            int ra = l >> 6, ka = l & 63;
            Al[ka][ra] = Ab[(size_t)(tr + ra) * 256 + kc + ka];
            Bl[ra][ka] = Bb[(size_t)(kc + ra) * 256 + tc + ka];  // ra=k, ka=c
        }
        __syncthreads();
#pragma unroll 4
        for (int k = 0; k < 64; ++k) {
            float a0 = Al[k][r0], a1 = Al[k][r0 + 1], a2 = Al[k][r0 + 2], a3 = Al[k][r0 + 3];
            float b0 = Bl[k][c0], b1 = Bl[k][c0 + 1], b2 = Bl[k][c0 + 2], b3 = Bl[k][c0 + 3];
            acc[0][0] = fmaf(a0, b0, acc[0][0]); acc[0][1] = fmaf(a0, b1, acc[0][1]);
            acc[0][2] = fmaf(a0, b2, acc[0][2]); acc[0][3] = fmaf(a0, b3, acc[0][3]);
            acc[1][0] = fmaf(a1, b0, acc[1][0]); acc[1][1] = fmaf(a1, b1, acc[1][1]);
            acc[1][2] = fmaf(a1, b2, acc[1][2]); acc[1][3] = fmaf(a1, b3, acc[1][3]);
            acc[2][0] = fmaf(a2, b0, acc[2][0]); acc[2][1] = fmaf(a2, b1, acc[2][1]);
            acc[2][2] = fmaf(a2, b2, acc[2][2]); acc[2][3] = fmaf(a2, b3, acc[2][3]);
            acc[3][0] = fmaf(a3, b0, acc[3][0]); acc[3][1] = fmaf(a3, b1, acc[3][1]);
            acc[3][2] = fmaf(a3, b2, acc[3][2]); acc[3][3] = fmaf(a3, b3, acc[3][3]);
        }
    }
#pragma unroll
    for (int i = 0; i < 4; ++i)
#pragma unroll
        for (int j = 0; j < 4; ++j) {
            int r = tr + r0 + i, c = tc + c0 + j;
            float v = scale * acc[i][j] + ((r == c) ? diag : 0.f);
            Ob[(size_t)r * 256 + c] = v;
        }
}

__global__ __launch_bounds__(256) void ns_gemm(const float* __restrict__ A,
                                               const float* __restrict__ B,
                                               float* __restrict__ O,
                                               float scale, float diag) {
    __shared__ float Al[64][68], Bl[64][68];
    size_t off = (size_t)blockIdx.y << 16;
    gemm_body(A + off, B + off, O + off, scale, diag, blockIdx.x, threadIdx.x, Al, Bl);
}

__global__ __launch_bounds__(256) void ns_gemm_pair(const float* __restrict__ Y,
                                                    const float* __restrict__ Mm,
                                                    const float* __restrict__ Z,
                                                    float* __restrict__ Yn,
                                                    float* __restrict__ Zn) {
    __shared__ float Al[64][68], Bl[64][68];
    size_t off = (size_t)blockIdx.y << 16;
    if (blockIdx.z == 0)
        gemm_body(Y + off, Mm + off, Yn + off, 0.5f, 0.f, blockIdx.x, threadIdx.x, Al, Bl);
    else
        gemm_body(Mm + off, Z + off, Zn + off, 0.5f, 0.f, blockIdx.x, threadIdx.x, Al, Bl);
}

// ---------------------------------------------------------------------------
// FC: outpre[b,o] += sum_k sqrt(trace[b])*Yf[b,k] * Wfc[o,k]
// grid: (512 k-chunks of 128, 4 o-tiles of 64)
// ---------------------------------------------------------------------------
__global__ __launch_bounds__(256) void fc_ker(const float* __restrict__ Yf,
                                              const float* __restrict__ trace,
                                              const float* __restrict__ Wfc,
                                              float* __restrict__ outpre) {
    int kc = blockIdx.x;
    int ot = blockIdx.y;
    int t = threadIdx.x;
    __shared__ float Wl[64][129];
    __shared__ float Vl[16][129];
#pragma unroll
    for (int i = 0; i < 32; ++i) {
        int l = i * 256 + t;
        int o = l >> 7, k = l & 127;
        Wl[o][k] = Wfc[(size_t)(ot * 64 + o) * 65536 + kc * 128 + k];
    }
#pragma unroll
    for (int i = 0; i < 8; ++i) {
        int l = i * 256 + t;
        int bb = l >> 7, k = l & 127;
        Vl[bb][k] = sqrtf(trace[bb]) * Yf[((size_t)bb << 16) + kc * 128 + k];
    }
    __syncthreads();
    int ol = t & 63, bg = t >> 6;
    float a0 = 0.f, a1 = 0.f, a2 = 0.f, a3 = 0.f;
    for (int k = 0; k < 128; ++k) {
        float w = Wl[ol][k];
        a0 = fmaf(w, Vl[bg * 4 + 0][k], a0);
        a1 = fmaf(w, Vl[bg * 4 + 1][k], a1);
        a2 = fmaf(w, Vl[bg * 4 + 2][k], a2);
        a3 = fmaf(w, Vl[bg * 4 + 3][k], a3);
    }
    int o = ot * 64 + ol;
    atomicAdd(&outpre[(bg * 4 + 0) * 256 + o], a0);
    atomicAdd(&outpre[(bg * 4 + 1) * 256 + o], a1);
    atomicAdd(&outpre[(bg * 4 + 2) * 256 + o], a2);
    atomicAdd(&outpre[(bg * 4 + 3) * 256 + o], a3);
}

__global__ void norm_ker(const float* __restrict__ outpre, const float* __restrict__ bfc,
                         float* __restrict__ dout) {
    int b = blockIdx.x, t = threadIdx.x;
    float v = outpre[b * 256 + t] + bfc[t];
    float q = v * v;
    for (int off = 32; off; off >>= 1) q += __shfl_xor(q, off);
    __shared__ float lq[4];
    __shared__ float snorm;
    if ((t & 63) == 0) lq[t >> 6] = q;
    __syncthreads();
    if (t == 0) snorm = fmaxf(sqrtf(lq[0] + lq[1] + lq[2] + lq[3]), 1e-12f);
    __syncthreads();
    dout[b * 256 + t] = v / snorm;
}

// ---------------------------------------------------------------------------
// Workspace layout (floats), total 61,456,384 floats = 234.4 MiB:
//   [0     .. 2560 )  stats   (atomic-accumulated; zeroed at start)
//   [2560  .. 6656 )  fsumb
//   [6656  .. 6672 )  trace   (atomic; zeroed at start)
//   [6672  .. 10768)  outpre  (atomic; zeroed at start)
//   [10768 .. 13328)  ss      (BN scale/shift, written before read)
//   [16384 .. +40.96M)  R: 256-ch activation buffer (L4 out = y4).
//                       Low 64-ch region doubles as P (L0/L2 out) — P dead
//                       before L4 writes R.
//   [R_end .. +20.48M)  Q: 128-ch buffer (L1/L3 out). Dead after L4;
//                       region reused for covM + Y0/Y1/Z0/Z1/Mb (6 x 4 MiB).
//                       covM zeroed by a second memset right before cov_ker.
// ---------------------------------------------------------------------------
extern "C" void kernel_launch(void* const* d_in, const int* in_sizes, int n_in,
                              void* d_out, int out_size, void* d_ws, size_t ws_size,
                              hipStream_t stream) {
    (void)in_sizes; (void)n_in; (void)out_size; (void)ws_size;
    const float* pts = (const float*)d_in[0];
    const float* Wm[5]; const float* gm[5]; const float* bm[5];
    for (int i = 0; i < 5; ++i) {
        Wm[i] = (const float*)d_in[1 + 3 * i];
        gm[i] = (const float*)d_in[2 + 3 * i];
        bm[i] = (const float*)d_in[3 + 3 * i];
    }
    const float* Wfc = (const float*)d_in[16];
    const float* bfc = (const float*)d_in[17];

    float* ws     = (float*)d_ws;
    float* stats  = ws;                  // 2560
    float* fsumb  = ws + 2560;           // 4096
    float* trace  = ws + 6656;           // 16
    float* outpre = ws + 6672;           // 4096
    float* ss     = ws + 10768;          // 2560
    float* R      = ws + 16384;          // 256ch fp32: 40,960,000 floats (y4)
    float* P      = R;                   // 64ch view (L0/L2 out)
    float* Q      = R + (size_t)NB * 256 * NPTS;   // 128ch: 20,480,000 floats
    // NS-phase aliases of the (then-dead) Q region:
    float* covM   = Q;
    float* Y0     = Q + 1048576;
    float* Y1     = Y0 + 1048576;
    float* Z0     = Y1 + 1048576;
    float* Z1     = Z0 + 1048576;
    float* Mb     = Z1 + 1048576;

    hipMemsetAsync(ws, 0, 16384 * sizeof(float), stream);

    // Layer 0 (3 -> 64)
    conv0_ker<<<dim3(NBN / 256), dim3(256), 0, stream>>>(pts, Wm[0], P);
    chan_stats<<<dim3(64, NB), dim3(256), 0, stream>>>(P, 64, stats);
    bn_finalize<<<dim3(1), dim3(256), 0, stream>>>(stats, gm[0], bm[0], 64, ss);
    // Layer 1 (64 -> 64)
    conv_bn_relu<64, 64><<<dim3(NBN / 256), dim3(256), 0, stream>>>(P, ss, Wm[1], Q);
    chan_stats<<<dim3(64, NB), dim3(256), 0, stream>>>(Q, 64, stats + 512);
    bn_finalize<<<dim3(1), dim3(256), 0, stream>>>(stats + 512, gm[1], bm[1], 64, ss + 512);
    // Layer 2 (64 -> 64)
    conv_bn_relu<64, 64><<<dim3(NBN / 256), dim3(256), 0, stream>>>(Q, ss + 512, Wm[2], P);
    chan_stats<<<dim3(64, NB), dim3(256), 0, stream>>>(P, 64, stats + 1024);
    bn_finalize<<<dim3(1), dim3(256), 0, stream>>>(stats + 1024, gm[2], bm[2], 64, ss + 1024);
    // Layer 3 (64 -> 128)
    conv_bn_relu<64, 128><<<dim3(NBN / 256), dim3(256), 0, stream>>>(P, ss + 1024, Wm[3], Q);
    chan_stats<<<dim3(128, NB), dim3(256), 0, stream>>>(Q, 128, stats + 1536);
    bn_finalize<<<dim3(1), dim3(256), 0, stream>>>(stats + 1536, gm[3], bm[3], 128, ss + 1536);
    // Layer 4 (128 -> 256); writes R (P is dead now)
    conv_bn_relu<128, 256><<<dim3(NBN / 256), dim3(256), 0, stream>>>(Q, ss + 1536, Wm[4], R);
    chan_stats<<<dim3(256, NB), dim3(256), 0, stream>>>(R, 256, stats + 2048);
    bn_finalize<<<dim3(1), dim3(256), 0, stream>>>(stats + 2048, gm[4], bm[4], 256, ss + 2048);

    // Covariance path (Q dead; its region now hosts covM/NS buffers)
    fsum_ker<<<dim3(256, NB), dim3(256), 0, stream>>>(R, ss + 2048, fsumb);
    hipMemsetAsync(covM, 0, 1048576 * sizeof(float), stream);
    cov_ker<<<dim3(8, 4, NB), dim3(256), 0, stream>>>(R, ss + 2048, covM);
    covfin_ker<<<dim3(256, NB), dim3(256), 0, stream>>>(covM, fsumb, Y0, trace);
    ns_init<<<dim3(4096), dim3(256), 0, stream>>>(Y0, Z0, trace);

    // Newton–Schulz iterations for principal sqrt
    float* Yc = Y0; float* Zc = Z0; float* Yn = Y1; float* Zn = Z1;
    for (int it = 0; it < NS_ITERS; ++it) {
        ns_gemm<<<dim3(16, NB), dim3(256), 0, stream>>>(Zc, Yc, Mb, -1.f, 3.f);
        ns_gemm_pair<<<dim3(16, NB, 2), dim3(256), 0, stream>>>(Yc, Mb, Zc, Yn, Zn);
        float* ty = Yc; Yc = Yn; Yn = ty;
        float* tz = Zc; Zc = Zn; Zn = tz;
    }

    fc_ker<<<dim3(512, 4), dim3(256), 0, stream>>>(Yc, trace, Wfc, outpre);
    norm_ker<<<dim3(NB), dim3(256), 0, stream>>>(outpre, bfc, (float*)d_out);
}

// Round 3
// 3208.560 us; speedup vs baseline: 1.6039x; 1.6039x over previous
//
#include <hip/hip_runtime.h>
#include <cmath>

constexpr int NB   = 16;      // batch
constexpr int NPTS = 10000;   // points per batch
constexpr int NBN  = NB * NPTS;   // 160000
constexpr int NS_ITERS = 18;

// ---------------------------------------------------------------------------
// Layer 0: 3 -> 64, no input BN
// ---------------------------------------------------------------------------
__global__ __launch_bounds__(256) void conv0_ker(const float* __restrict__ pts,
                                                 const float* __restrict__ W,
                                                 float* __restrict__ y) {
    int g = blockIdx.x * 256 + threadIdx.x;          // 0..159999
    int b = g / NPTS;
    int n = g - b * NPTS;
    float p0 = pts[3 * (size_t)g + 0];
    float p1 = pts[3 * (size_t)g + 1];
    float p2 = pts[3 * (size_t)g + 2];
    float* yp = y + ((size_t)b * 64) * NPTS + n;
    for (int o = 0; o < 64; ++o) {
        float v = W[3 * o] * p0 + W[3 * o + 1] * p1 + W[3 * o + 2] * p2;
        yp[(size_t)o * NPTS] = v;
    }
}

// ---------------------------------------------------------------------------
// Tiled GEMM conv layer: y[b, ob+o, n] = sum_c W[ob+o, c] * relu(bn(x[b, c, n]))
// Block: 64 outputs x 128 points. K chunked by 32. Grid: (79 ntiles, COUT/64, NB)
// ---------------------------------------------------------------------------
template <int CIN, int COUT>
__global__ __launch_bounds__(256) void conv_gemm(const float* __restrict__ xin,
                                                 const float* __restrict__ ss,
                                                 const float* __restrict__ W,
                                                 float* __restrict__ y) {
    __shared__ float Wl[64][CIN + 1];
    __shared__ float Xl[32][132];

    const int tid = threadIdx.x;
    const int nb  = blockIdx.x * 128;
    const int ob  = blockIdx.y * 64;
    const int b   = blockIdx.z;

    // Stage weight tile: Wl[o][c] = W[(ob+o)*CIN + c]. Coalesced global reads,
    // conflict-free LDS writes (consecutive c -> consecutive banks, pad +1).
#pragma unroll
    for (int i = 0; i < CIN / 4; ++i) {
        int l = i * 256 + tid;
        int o = l / CIN, c = l % CIN;
        Wl[o][c] = W[(size_t)(ob + o) * CIN + c];
    }

    const int o0 = (tid >> 4) * 4;      // 4 output channels per thread
    const int n0 = (tid & 15) * 8;      // 8 points per thread

    float acc[4][8];
#pragma unroll
    for (int i = 0; i < 4; ++i)
#pragma unroll
        for (int j = 0; j < 8; ++j) acc[i][j] = 0.f;

    const int n4 = (tid & 31) * 4;
    const int kk0 = tid >> 5;

    for (int kc = 0; kc < CIN; kc += 32) {
        __syncthreads();   // protect Xl (prev iter readers) / Wl ready (first iter)
        const float* xbase = xin + ((size_t)(b * CIN + kc)) * NPTS;
#pragma unroll
        for (int i = 0; i < 4; ++i) {
            int kk = kk0 + i * 8;
            int ng = nb + n4;
            float4 v = make_float4(0.f, 0.f, 0.f, 0.f);
            if (ng + 4 <= NPTS) {
                v = *(const float4*)(xbase + (size_t)kk * NPTS + ng);
                float sc = ss[kc + kk], sh = ss[256 + kc + kk];
                v.x = fmaxf(fmaf(v.x, sc, sh), 0.f);
                v.y = fmaxf(fmaf(v.y, sc, sh), 0.f);
                v.z = fmaxf(fmaf(v.z, sc, sh), 0.f);
                v.w = fmaxf(fmaf(v.w, sc, sh), 0.f);
            }
            *(float4*)&Xl[kk][n4] = v;
        }
        __syncthreads();
#pragma unroll
        for (int k = 0; k < 32; ++k) {
            float w0 = Wl[o0 + 0][kc + k];
            float w1 = Wl[o0 + 1][kc + k];
            float w2 = Wl[o0 + 2][kc + k];
            float w3 = Wl[o0 + 3][kc + k];
            float4 xa = *(const float4*)&Xl[k][n0];
            float4 xb = *(const float4*)&Xl[k][n0 + 4];
            float xv[8] = {xa.x, xa.y, xa.z, xa.w, xb.x, xb.y, xb.z, xb.w};
#pragma unroll
            for (int j = 0; j < 8; ++j) {
                acc[0][j] = fmaf(w0, xv[j], acc[0][j]);
                acc[1][j] = fmaf(w1, xv[j], acc[1][j]);
                acc[2][j] = fmaf(w2, xv[j], acc[2][j]);
                acc[3][j] = fmaf(w3, xv[j], acc[3][j]);
            }
        }
    }

    // Epilogue: guarded vectorized stores
    const int ng = nb + n0;
#pragma unroll
    for (int i = 0; i < 4; ++i) {
        float* row = y + ((size_t)(b * COUT + ob + o0 + i)) * NPTS + ng;
        if (ng + 8 <= NPTS) {
            *(float4*)row       = make_float4(acc[i][0], acc[i][1], acc[i][2], acc[i][3]);
            *(float4*)(row + 4) = make_float4(acc[i][4], acc[i][5], acc[i][6], acc[i][7]);
        } else {
#pragma unroll
            for (int j = 0; j < 8; ++j)
                if (ng + j < NPTS) row[j] = acc[i][j];
        }
    }
}

// ---------------------------------------------------------------------------
// Per-channel sum / sumsq over (batch, points)  -> stats[c], stats[C+c]
// ---------------------------------------------------------------------------
__global__ void chan_stats(const float* __restrict__ y, int C, float* __restrict__ stats) {
    int c = blockIdx.x, b = blockIdx.y, t = threadIdx.x;
    const float* p = y + ((size_t)(b * C + c)) * NPTS;
    float s = 0.f, q = 0.f;
    for (int n = t; n < NPTS; n += 256) {
        float v = p[n];
        s += v;
        q = fmaf(v, v, q);
    }
    for (int off = 32; off; off >>= 1) {
        s += __shfl_down(s, off);
        q += __shfl_down(q, off);
    }
    __shared__ float ls[4], lq[4];
    if ((t & 63) == 0) { ls[t >> 6] = s; lq[t >> 6] = q; }
    __syncthreads();
    if (t == 0) {
        atomicAdd(&stats[c],     ls[0] + ls[1] + ls[2] + ls[3]);
        atomicAdd(&stats[C + c], lq[0] + lq[1] + lq[2] + lq[3]);
    }
}

__global__ void bn_finalize(const float* __restrict__ stats, const float* __restrict__ g,
                            const float* __restrict__ bi, int C, float* __restrict__ ss) {
    int c = threadIdx.x;
    if (c < C) {
        float mu  = stats[c] * (1.f / NBN);
        float var = stats[C + c] * (1.f / NBN) - mu * mu;
        float r = rsqrtf(var + 1e-5f);
        float s = g[c] * r;
        ss[c] = s;
        ss[256 + c] = bi[c] - mu * s;
    }
}

// ---------------------------------------------------------------------------
// Per-batch channel sums of final features f = relu(bn(y4))
// ---------------------------------------------------------------------------
__global__ void fsum_ker(const float* __restrict__ y4, const float* __restrict__ ss,
                         float* __restrict__ fsumb) {
    int c = blockIdx.x, b = blockIdx.y, t = threadIdx.x;
    const float* p = y4 + ((size_t)(b * 256 + c)) * NPTS;
    float sc = ss[c], sh = ss[256 + c];
    float s = 0.f;
    for (int n = t; n < NPTS; n += 256) {
        float v = fmaf(p[n], sc, sh);
        s += fmaxf(v, 0.f);
    }
    for (int off = 32; off; off >>= 1) s += __shfl_down(s, off);
    __shared__ float ls[4];
    if ((t & 63) == 0) ls[t >> 6] = s;
    __syncthreads();
    if (t == 0) fsumb[b * 256 + c] = ls[0] + ls[1] + ls[2] + ls[3];
}

// ---------------------------------------------------------------------------
// Raw second moment: covM[b] += F_b^T F_b  (128x128 tiles, N split in 8 chunks)
// grid: (8 chunks, 4 tiles, 16 batches)
// ---------------------------------------------------------------------------
__global__ __launch_bounds__(256) void cov_ker(const float* __restrict__ y4,
                                               const float* __restrict__ ss,
                                               float* __restrict__ covM) {
    int chunk = blockIdx.x;
    int tile  = blockIdx.y;
    int b     = blockIdx.z;
    int ti = tile >> 1, tj = tile & 1;
    int t = threadIdx.x;
    __shared__ float At[2][32][132];   // [half][point][channel], padded
    float acc[8][8];
#pragma unroll
    for (int i = 0; i < 8; ++i)
#pragma unroll
        for (int j = 0; j < 8; ++j) acc[i][j] = 0.f;

    int n0c = chunk * 1250;
    int r0 = (t & 15) * 8, c0 = (t >> 4) * 8;
    for (int pp = 0; pp < 40; ++pp) {
        int base = pp * 32;
        __syncthreads();
#pragma unroll
        for (int half = 0; half < 2; ++half) {
            int panel = (half ? tj : ti) * 128;
#pragma unroll
            for (int i = 0; i < 16; ++i) {
                int l = i * 256 + t;
                int c = l >> 5, p = l & 31;
                float v = 0.f;
                if (base + p < 1250) {
                    float raw = y4[((size_t)(b * 256 + panel + c)) * NPTS + n0c + base + p];
                    raw = fmaf(raw, ss[panel + c], ss[256 + panel + c]);
                    v = fmaxf(raw, 0.f);
                }
                At[half][p][c] = v;
            }
        }
        __syncthreads();
#pragma unroll 4
        for (int p = 0; p < 32; ++p) {
            float ar[8], ac[8];
#pragma unroll
            for (int i = 0; i < 8; ++i) ar[i] = At[0][p][r0 + i];
#pragma unroll
            for (int j = 0; j < 8; ++j) ac[j] = At[1][p][c0 + j];
#pragma unroll
            for (int i = 0; i < 8; ++i)
#pragma unroll
                for (int j = 0; j < 8; ++j) acc[i][j] = fmaf(ar[i], ac[j], acc[i][j]);
        }
    }
#pragma unroll
    for (int i = 0; i < 8; ++i)
#pragma unroll
        for (int j = 0; j < 8; ++j) {
            size_t idx = ((size_t)b << 16) + (size_t)(ti * 128 + r0 + i) * 256 + tj * 128 + c0 + j;
            atomicAdd(&covM[idx], acc[i][j]);
        }
}

// ---------------------------------------------------------------------------
// cov = M/N - m (.) fbar^T - fbar (.) m^T + m m^T ; trace via diagonal atomics
// grid: (256 rows, 16 batches), 256 threads = cols
// ---------------------------------------------------------------------------
__global__ void covfin_ker(const float* __restrict__ covM, const float* __restrict__ fsumb,
                           float* __restrict__ Y0, float* __restrict__ trace) {
    int r = blockIdx.x, b = blockIdx.y, c = threadIdx.x;
    float fbr = fsumb[b * 256 + r] * (1.f / NPTS);
    float fbc = fsumb[b * 256 + c] * (1.f / NPTS);
    float mr = 0.f, mc = 0.f;
    for (int q = 0; q < NB; ++q) {
        mr += fsumb[q * 256 + r];
        mc += fsumb[q * 256 + c];
    }
    mr *= (1.f / NBN);
    mc *= (1.f / NBN);
    size_t idx = ((size_t)b << 16) + ((size_t)r << 8) + c;
    float v = covM[idx] * (1.f / NPTS) - fbr * mc - mr * fbc + mr * mc;
    Y0[idx] = v;
    if (c == r) atomicAdd(&trace[b], v);
}

__global__ void ns_init(float* __restrict__ Y0, float* __restrict__ Z0,
                        const float* __restrict__ trace) {
    int i = blockIdx.x * 256 + threadIdx.x;   // 16*65536 total
    int b = i >> 16, rc = i & 65535;
    float inv = 1.f / trace[b];
    Y0[i] *= inv;
    Z0[i] = ((rc >> 8) == (rc & 255)) ? 1.f : 0.f;
}

// ---------------------------------------------------------------------------
// 256x256 batched GEMM tile body: O = diag*I + scale*(A.B), 64x64 tiles
// ---------------------------------------------------------------------------
__device__ __forceinline__ void gemm_body(const float* __restrict__ Ab,
                                          const float* __restrict__ Bb,
                                          float* __restrict__ Ob,
                                          float scale, float diag, int tile, int t,
                                          float (*Al)[68], float (*Bl)[68]) {
    int tr = (tile >> 2) * 64, tc = (tile & 3) * 64;
    int r0 = (t & 15) * 4, c0 = (t >> 4) * 4;
    float acc[4][4];
#pragma unroll
    for (int i = 0; i < 4; ++i)
#pragma unroll
        for (int j = 0; j < 4; ++j) acc[i][j] = 0.f;

    for (int kc = 0; kc < 256; kc += 64) {
        __syncthreads();
#pragma unroll
        for (int i = 0; i < 16; ++i) {
            int l = i * 256 + t;
            int ra = l >> 6, ka = l & 63;
            Al[ka][ra] = Ab[(size_t)(tr + ra) * 256 + kc + ka];
            Bl[ra][ka] = Bb[(size_t)(kc + ra) * 256 + tc + ka];  // ra=k, ka=c
        }
        __syncthreads();
#pragma unroll 4
        for (int k = 0; k < 64; ++k) {
            float a0 = Al[k][r0], a1 = Al[k][r0 + 1], a2 = Al[k][r0 + 2], a3 = Al[k][r0 + 3];
            float b0 = Bl[k][c0], b1 = Bl[k][c0 + 1], b2 = Bl[k][c0 + 2], b3 = Bl[k][c0 + 3];
            acc[0][0] = fmaf(a0, b0, acc[0][0]); acc[0][1] = fmaf(a0, b1, acc[0][1]);
            acc[0][2] = fmaf(a0, b2, acc[0][2]); acc[0][3] = fmaf(a0, b3, acc[0][3]);
            acc[1][0] = fmaf(a1, b0, acc[1][0]); acc[1][1] = fmaf(a1, b1, acc[1][1]);
            acc[1][2] = fmaf(a1, b2, acc[1][2]); acc[1][3] = fmaf(a1, b3, acc[1][3]);
            acc[2][0] = fmaf(a2, b0, acc[2][0]); acc[2][1] = fmaf(a2, b1, acc[2][1]);
            acc[2][2] = fmaf(a2, b2, acc[2][2]); acc[2][3] = fmaf(a2, b3, acc[2][3]);
            acc[3][0] = fmaf(a3, b0, acc[3][0]); acc[3][1] = fmaf(a3, b1, acc[3][1]);
            acc[3][2] = fmaf(a3, b2, acc[3][2]); acc[3][3] = fmaf(a3, b3, acc[3][3]);
        }
    }
#pragma unroll
    for (int i = 0; i < 4; ++i)
#pragma unroll
        for (int j = 0; j < 4; ++j) {
            int r = tr + r0 + i, c = tc + c0 + j;
            float v = scale * acc[i][j] + ((r == c) ? diag : 0.f);
            Ob[(size_t)r * 256 + c] = v;
        }
}

__global__ __launch_bounds__(256) void ns_gemm(const float* __restrict__ A,
                                               const float* __restrict__ B,
                                               float* __restrict__ O,
                                               float scale, float diag) {
    __shared__ float Al[64][68], Bl[64][68];
    size_t off = (size_t)blockIdx.y << 16;
    gemm_body(A + off, B + off, O + off, scale, diag, blockIdx.x, threadIdx.x, Al, Bl);
}

__global__ __launch_bounds__(256) void ns_gemm_pair(const float* __restrict__ Y,
                                                    const float* __restrict__ Mm,
                                                    const float* __restrict__ Z,
                                                    float* __restrict__ Yn,
                                                    float* __restrict__ Zn) {
    __shared__ float Al[64][68], Bl[64][68];
    size_t off = (size_t)blockIdx.y << 16;
    if (blockIdx.z == 0)
        gemm_body(Y + off, Mm + off, Yn + off, 0.5f, 0.f, blockIdx.x, threadIdx.x, Al, Bl);
    else
        gemm_body(Mm + off, Z + off, Zn + off, 0.5f, 0.f, blockIdx.x, threadIdx.x, Al, Bl);
}

// ---------------------------------------------------------------------------
// FC: outpre[b,o] += sum_k sqrt(trace[b])*Yf[b,k] * Wfc[o,k]
// grid: (512 k-chunks of 128, 4 o-tiles of 64)
// ---------------------------------------------------------------------------
__global__ __launch_bounds__(256) void fc_ker(const float* __restrict__ Yf,
                                              const float* __restrict__ trace,
                                              const float* __restrict__ Wfc,
                                              float* __restrict__ outpre) {
    int kc = blockIdx.x;
    int ot = blockIdx.y;
    int t = threadIdx.x;
    __shared__ float Wl[64][129];
    __shared__ float Vl[16][129];
#pragma unroll
    for (int i = 0; i < 32; ++i) {
        int l = i * 256 + t;
        int o = l >> 7, k = l & 127;
        Wl[o][k] = Wfc[(size_t)(ot * 64 + o) * 65536 + kc * 128 + k];
    }
#pragma unroll
    for (int i = 0; i < 8; ++i) {
        int l = i * 256 + t;
        int bb = l >> 7, k = l & 127;
        Vl[bb][k] = sqrtf(trace[bb]) * Yf[((size_t)bb << 16) + kc * 128 + k];
    }
    __syncthreads();
    int ol = t & 63, bg = t >> 6;
    float a0 = 0.f, a1 = 0.f, a2 = 0.f, a3 = 0.f;
    for (int k = 0; k < 128; ++k) {
        float w = Wl[ol][k];
        a0 = fmaf(w, Vl[bg * 4 + 0][k], a0);
        a1 = fmaf(w, Vl[bg * 4 + 1][k], a1);
        a2 = fmaf(w, Vl[bg * 4 + 2][k], a2);
        a3 = fmaf(w, Vl[bg * 4 + 3][k], a3);
    }
    int o = ot * 64 + ol;
    atomicAdd(&outpre[(bg * 4 + 0) * 256 + o], a0);
    atomicAdd(&outpre[(bg * 4 + 1) * 256 + o], a1);
    atomicAdd(&outpre[(bg * 4 + 2) * 256 + o], a2);
    atomicAdd(&outpre[(bg * 4 + 3) * 256 + o], a3);
}

__global__ void norm_ker(const float* __restrict__ outpre, const float* __restrict__ bfc,
                         float* __restrict__ dout) {
    int b = blockIdx.x, t = threadIdx.x;
    float v = outpre[b * 256 + t] + bfc[t];
    float q = v * v;
    for (int off = 32; off; off >>= 1) q += __shfl_xor(q, off);
    __shared__ float lq[4];
    __shared__ float snorm;
    if ((t & 63) == 0) lq[t >> 6] = q;
    __syncthreads();
    if (t == 0) snorm = fmaxf(sqrtf(lq[0] + lq[1] + lq[2] + lq[3]), 1e-12f);
    __syncthreads();
    dout[b * 256 + t] = v / snorm;
}

// ---------------------------------------------------------------------------
// Workspace layout (floats), total ~234 MiB — see round-1 notes.
// ---------------------------------------------------------------------------
extern "C" void kernel_launch(void* const* d_in, const int* in_sizes, int n_in,
                              void* d_out, int out_size, void* d_ws, size_t ws_size,
                              hipStream_t stream) {
    (void)in_sizes; (void)n_in; (void)out_size; (void)ws_size;
    const float* pts = (const float*)d_in[0];
    const float* Wm[5]; const float* gm[5]; const float* bm[5];
    for (int i = 0; i < 5; ++i) {
        Wm[i] = (const float*)d_in[1 + 3 * i];
        gm[i] = (const float*)d_in[2 + 3 * i];
        bm[i] = (const float*)d_in[3 + 3 * i];
    }
    const float* Wfc = (const float*)d_in[16];
    const float* bfc = (const float*)d_in[17];

    float* ws     = (float*)d_ws;
    float* stats  = ws;                  // 2560
    float* fsumb  = ws + 2560;           // 4096
    float* trace  = ws + 6656;           // 16
    float* outpre = ws + 6672;           // 4096
    float* ss     = ws + 10768;          // 2560
    float* R      = ws + 16384;          // 256ch fp32: 40,960,000 floats (y4)
    float* P      = R;                   // 64ch view (L0/L2 out)
    float* Q      = R + (size_t)NB * 256 * NPTS;   // 128ch: 20,480,000 floats
    // NS-phase aliases of the (then-dead) Q region:
    float* covM   = Q;
    float* Y0     = Q + 1048576;
    float* Y1     = Y0 + 1048576;
    float* Z0     = Y1 + 1048576;
    float* Z1     = Z0 + 1048576;
    float* Mb     = Z1 + 1048576;

    hipMemsetAsync(ws, 0, 16384 * sizeof(float), stream);

    // Layer 0 (3 -> 64)
    conv0_ker<<<dim3(NBN / 256), dim3(256), 0, stream>>>(pts, Wm[0], P);
    chan_stats<<<dim3(64, NB), dim3(256), 0, stream>>>(P, 64, stats);
    bn_finalize<<<dim3(1), dim3(256), 0, stream>>>(stats, gm[0], bm[0], 64, ss);
    // Layer 1 (64 -> 64)
    conv_gemm<64, 64><<<dim3(79, 1, NB), dim3(256), 0, stream>>>(P, ss, Wm[1], Q);
    chan_stats<<<dim3(64, NB), dim3(256), 0, stream>>>(Q, 64, stats + 512);
    bn_finalize<<<dim3(1), dim3(256), 0, stream>>>(stats + 512, gm[1], bm[1], 64, ss + 512);
    // Layer 2 (64 -> 64)
    conv_gemm<64, 64><<<dim3(79, 1, NB), dim3(256), 0, stream>>>(Q, ss + 512, Wm[2], P);
    chan_stats<<<dim3(64, NB), dim3(256), 0, stream>>>(P, 64, stats + 1024);
    bn_finalize<<<dim3(1), dim3(256), 0, stream>>>(stats + 1024, gm[2], bm[2], 64, ss + 1024);
    // Layer 3 (64 -> 128)
    conv_gemm<64, 128><<<dim3(79, 2, NB), dim3(256), 0, stream>>>(P, ss + 1024, Wm[3], Q);
    chan_stats<<<dim3(128, NB), dim3(256), 0, stream>>>(Q, 128, stats + 1536);
    bn_finalize<<<dim3(1), dim3(256), 0, stream>>>(stats + 1536, gm[3], bm[3], 128, ss + 1536);
    // Layer 4 (128 -> 256); writes R (P is dead now)
    conv_gemm<128, 256><<<dim3(79, 4, NB), dim3(256), 0, stream>>>(Q, ss + 1536, Wm[4], R);
    chan_stats<<<dim3(256, NB), dim3(256), 0, stream>>>(R, 256, stats + 2048);
    bn_finalize<<<dim3(1), dim3(256), 0, stream>>>(stats + 2048, gm[4], bm[4], 256, ss + 2048);

    // Covariance path (Q dead; its region now hosts covM/NS buffers)
    fsum_ker<<<dim3(256, NB), dim3(256), 0, stream>>>(R, ss + 2048, fsumb);
    hipMemsetAsync(covM, 0, 1048576 * sizeof(float), stream);
    cov_ker<<<dim3(8, 4, NB), dim3(256), 0, stream>>>(R, ss + 2048, covM);
    covfin_ker<<<dim3(256, NB), dim3(256), 0, stream>>>(covM, fsumb, Y0, trace);
    ns_init<<<dim3(4096), dim3(256), 0, stream>>>(Y0, Z0, trace);

    // Newton–Schulz iterations for principal sqrt
    float* Yc = Y0; float* Zc = Z0; float* Yn = Y1; float* Zn = Z1;
    for (int it = 0; it < NS_ITERS; ++it) {
        ns_gemm<<<dim3(16, NB), dim3(256), 0, stream>>>(Zc, Yc, Mb, -1.f, 3.f);
        ns_gemm_pair<<<dim3(16, NB, 2), dim3(256), 0, stream>>>(Yc, Mb, Zc, Yn, Zn);
        float* ty = Yc; Yc = Yn; Yn = ty;
        float* tz = Zc; Zc = Zn; Zn = tz;
    }

    fc_ker<<<dim3(512, 4), dim3(256), 0, stream>>>(Yc, trace, Wfc, outpre);
    norm_ker<<<dim3(NB), dim3(256), 0, stream>>>(outpre, bfc, (float*)d_out);
}